// Round 10
// baseline (70.472 us; speedup 1.0000x reference)
//
#include <hip/hip_runtime.h>
#include <stdint.h>

using bf16x8 = __attribute__((ext_vector_type(8))) __bf16;
using f32x4v = __attribute__((ext_vector_type(4))) float;
using f32x2v = __attribute__((ext_vector_type(2))) float;

__device__ __forceinline__ unsigned int f2bf(float f) {
  unsigned int u = __float_as_uint(f);
  return (u + 0x7FFFu + ((u >> 16) & 1u)) >> 16;  // RNE f32->bf16
}

// =====================================================================
// k0b: codebook f32 [1024][256] -> bf16 in MFMA FRAGMENT order + 0.5||e||^2
// (R4-verified) addr = ((code>>4)*8 + kk)*1024 + (g*16 + (code&15))*16 + j*2
// => 64-code chunk ch = contiguous 32KB [ch*32768, +32768).
// =====================================================================
__global__ __launch_bounds__(64) void k0b_cb(const float* __restrict__ cb,
                                             char* __restrict__ cbb,
                                             float* __restrict__ hn) {
  const int code = blockIdx.x, l = threadIdx.x;
  const float4 v = *(const float4*)(cb + code * 256 + l * 4);
  float ss = v.x * v.x + v.y * v.y + v.z * v.z + v.w * v.w;
  uint2 p;
  p.x = f2bf(v.x) | (f2bf(v.y) << 16);
  p.y = f2bf(v.z) | (f2bf(v.w) << 16);
  const int addr = (((code >> 4) * 8 + (l >> 3)) << 10) +
                   ((((l >> 1) & 3) * 16 + (code & 15)) << 4) + (l & 1) * 8;
  *(uint2*)(cbb + addr) = p;
#pragma unroll
  for (int s = 32; s; s >>= 1) ss += __shfl_down(ss, s, 64);
  if (l == 0) hn[code] = 0.5f * ss;
}

// =====================================================================
// k1_fused: 512 blocks x 256 thr (4 waves 2x2), block = 128 rows.
// M=64/wave: A = 32 bf16x8 regs; per chunk/wave: 16 ds_read_b128 + 64 MFMA.
// B: 16 chunks x 64 codes, dbuf 2x32KB, counted-vmcnt pipeline (no drain):
//   prologue stage(0),stage(1); loop: vmcnt(8)->barrier->compute->barrier->
//   stage(ch+2). 8 gload_lds issues/wave/chunk (1KB each, wave-level).
// A-stage: float4 z loads, XOR slot swizzle (slot = r15^g) both sides.
// Epilogue: gather -> bf16 ef[128][258] -> b128 pair reads, f32x2 stores.
// LDS (72768 B => 2 blocks/CU):
//   [0,65536) A-scratch / B dbuf; ef overlay [0,66048)
//   hn [66048,70144) lv [70144,71168) li [71168,72192)
//   idx [72192,72704) red [72704,72768)
// =====================================================================
#define HN_OFF   66048
#define LV_OFF   70144
#define LI_OFF   71168
#define IDX_OFF  72192
#define RED_OFF  72704
#define LDS_SZ   72768

__global__ __launch_bounds__(256, 2) void k1_fused(const float* __restrict__ z,
                                                   const float* __restrict__ cb,
                                                   const char* __restrict__ cbb,
                                                   const float* __restrict__ hn,
                                                   float* __restrict__ out,
                                                   float* __restrict__ pz2,
                                                   float* __restrict__ ps) {
  extern __shared__ char smem[];
  const int t = threadIdx.x, w = t >> 6, lane = t & 63;
  const int l15 = lane & 15, g4 = lane >> 4;
  const int wr = w >> 1, wc = w & 1;
  const int bid = blockIdx.x;
  const int b = bid >> 5, hw0 = (bid & 31) << 7;
  const float* zb = z + ((size_t)b << 20) + hw0;

  // ---- A stage: 128 rows x 256 ch, float4 loads, XOR-swizzled LDS ----
  // thread: row-quad q = t&31 (rows q*4..+3), octet o = oi*8 + (t>>5).
  const int q = t & 31, oslot = t >> 5;
  float ss = 0.f;
#pragma unroll 1
  for (int oi = 0; oi < 4; ++oi) {
    const int o = oi * 8 + oslot;  // channel octet 0..31
    float4 f[8];
#pragma unroll
    for (int j = 0; j < 8; ++j)
      f[j] = *(const float4*)(zb + (size_t)(o * 8 + j) * 4096 + q * 4);
#pragma unroll
    for (int j = 0; j < 8; ++j)
      ss += f[j].x * f[j].x + f[j].y * f[j].y + f[j].z * f[j].z + f[j].w * f[j].w;
    const int kk = o >> 2, g = o & 3;
#pragma unroll
    for (int k = 0; k < 4; ++k) {
      const int row = q * 4 + k;
      const int band = row >> 5, rb = row & 31;
      const int mb = rb >> 4, r15 = rb & 15;
      uint4 q4;
      q4.x = f2bf(((const float*)&f[0])[k]) | (f2bf(((const float*)&f[1])[k]) << 16);
      q4.y = f2bf(((const float*)&f[2])[k]) | (f2bf(((const float*)&f[3])[k]) << 16);
      q4.z = f2bf(((const float*)&f[4])[k]) | (f2bf(((const float*)&f[5])[k]) << 16);
      q4.w = f2bf(((const float*)&f[6])[k]) | (f2bf(((const float*)&f[7])[k]) << 16);
      *(uint4*)(smem + (band << 14) + (((mb << 3) + kk) << 10) +
                (((g << 4) + (r15 ^ g)) << 4)) = q4;
    }
  }
  *(float4*)(smem + HN_OFF + t * 16) = *(const float4*)(hn + 4 * t);
  __syncthreads();

  // ---- A panel -> registers (32 frags = 128 VGPR) ----
  bf16x8 A[4][8];
#pragma unroll
  for (int mb4 = 0; mb4 < 4; ++mb4)
#pragma unroll
    for (int kk = 0; kk < 8; ++kk) {
      const int band = wr * 2 + (mb4 >> 1), mb = mb4 & 1;
      A[mb4][kk] = *(const bf16x8*)(smem + (band << 14) + (((mb << 3) + kk) << 10) +
                                    (((g4 << 4) + (l15 ^ g4)) << 4));
    }
  __syncthreads();  // scratch reads done before B staging overwrites

  // ---- B chunk stage: 32 KB = 8 issues/wave x 1 KB x 4 waves ----
  auto stageB = [&](int buf, int ch) {
#pragma unroll
    for (int i = 0; i < 8; ++i) {
      __builtin_amdgcn_global_load_lds(
          (const __attribute__((address_space(1))) unsigned int*)
              (cbb + ((size_t)ch << 15) + (w << 13) + (i << 10) + (lane << 4)),
          (__attribute__((address_space(3))) unsigned int*)
              (smem + (buf << 15) + (w << 13) + (i << 10)),
          16, 0, 0);
    }
  };
  stageB(0, 0);
  stageB(1, 1);

  float bestv[4][4];
  int besti[4][4];
#pragma unroll
  for (int m = 0; m < 4; ++m)
#pragma unroll
    for (int i = 0; i < 4; ++i) { bestv[m][i] = -3.4e38f; besti[m][i] = 0; }

  // ---- main loop: 16 chunks x 64 codes, counted-vmcnt pipeline ----
  for (int ch = 0; ch < 16; ++ch) {
    const int cur = ch & 1;
    // own wave's 8 issues for chunk ch must be done; ch+1's 8 may remain.
    if (ch < 15) asm volatile("s_waitcnt vmcnt(8)" ::: "memory");
    else         asm volatile("s_waitcnt vmcnt(0)" ::: "memory");
    __builtin_amdgcn_s_barrier();   // all waves' DMA for ch complete
    __builtin_amdgcn_sched_barrier(0);
    const float hnv0 = *(const float*)(smem + HN_OFF + (ch * 64 + wc * 32 + l15) * 4);
    const float hnv1 = *(const float*)(smem + HN_OFF + (ch * 64 + wc * 32 + 16 + l15) * 4);
    f32x4v acc[4][2];
#pragma unroll
    for (int m = 0; m < 4; ++m)
#pragma unroll
      for (int n = 0; n < 2; ++n) acc[m][n] = (f32x4v){0.f, 0.f, 0.f, 0.f};
    __builtin_amdgcn_s_setprio(1);
#pragma unroll
    for (int kk = 0; kk < 8; ++kk) {
      const bf16x8 b0 = *(const bf16x8*)(smem + (cur << 15) +
                        (((wc * 2 + 0) * 8 + kk) << 10) + (lane << 4));
      const bf16x8 b1 = *(const bf16x8*)(smem + (cur << 15) +
                        (((wc * 2 + 1) * 8 + kk) << 10) + (lane << 4));
#pragma unroll
      for (int m = 0; m < 4; ++m) {
        acc[m][0] = __builtin_amdgcn_mfma_f32_16x16x32_bf16(A[m][kk], b0, acc[m][0], 0, 0, 0);
        acc[m][1] = __builtin_amdgcn_mfma_f32_16x16x32_bf16(A[m][kk], b1, acc[m][1], 0, 0, 0);
      }
    }
    __builtin_amdgcn_s_setprio(0);
#pragma unroll
    for (int m = 0; m < 4; ++m)
#pragma unroll
      for (int n = 0; n < 2; ++n) {
        const int col = ch * 64 + wc * 32 + n * 16 + l15;
        const float hv = n ? hnv1 : hnv0;
#pragma unroll
        for (int i = 0; i < 4; ++i) {
          const float vv = acc[m][n][i] - hv;
          if (vv > bestv[m][i]) { bestv[m][i] = vv; besti[m][i] = col; }
        }
      }
    __builtin_amdgcn_sched_barrier(0);
    __builtin_amdgcn_s_barrier();   // all waves done reading buf[cur]
    if (ch + 2 < 16) stageB(cur, ch + 2);
  }

  // ---- cross-lane argmax within 16-col groups ----
#pragma unroll
  for (int m = 0; m < 4; ++m)
#pragma unroll
    for (int i = 0; i < 4; ++i) {
      float v = bestv[m][i];
      int ix = besti[m][i];
#pragma unroll
      for (int s = 1; s < 16; s <<= 1) {
        const float ov = __shfl_xor(v, s, 64);
        const int oi = __shfl_xor(ix, s, 64);
        if (ov > v || (ov == v && oi < ix)) { v = ov; ix = oi; }
      }
      bestv[m][i] = v; besti[m][i] = ix;
    }

  float* lv = (float*)(smem + LV_OFF);
  int* li = (int*)(smem + LI_OFF);
  int* idx_s = (int*)(smem + IDX_OFF);
  if (l15 == 0) {
#pragma unroll
    for (int m = 0; m < 4; ++m)
#pragma unroll
      for (int i = 0; i < 4; ++i) {
        const int row = wr * 64 + m * 16 + g4 * 4 + i;
        lv[wc * 128 + row] = bestv[m][i];
        li[wc * 128 + row] = besti[m][i];
      }
  }
  __syncthreads();
  float sv = 0.f;
  if (t < 128) {
    const float v0 = lv[t], v1 = lv[128 + t];
    const int i0 = li[t], i1 = li[128 + t];
    const bool take1 = (v1 > v0) || (v1 == v0 && i1 < i0);
    sv = take1 ? v1 : v0;
    idx_s[t] = take1 ? i1 : i0;
  }
  // block reductions: pz2 = Sigma z^2 (exact cover), ps = Sigma s*
  float zz = ss;
#pragma unroll
  for (int s = 32; s; s >>= 1) {
    zz += __shfl_down(zz, s, 64);
    sv += __shfl_down(sv, s, 64);
  }
  float* red = (float*)(smem + RED_OFF);
  if (lane == 0) { red[w] = zz; red[4 + w] = sv; }
  __syncthreads();  // idx_s visible; B bufs dead -> ef may overlay
  if (t == 0) {
    pz2[bid] = red[0] + red[1] + red[2] + red[3];
    ps[bid] = red[4] + red[5] + red[6] + red[7];
  }

  // ---- epilogue: chosen rows -> bf16 ef [128][258] ----
#pragma unroll 4
  for (int rr = 0; rr < 32; ++rr) {
    const int r = w * 32 + rr;
    const int code = idx_s[r];  // wave-uniform broadcast
    const float4 ev = *(const float4*)(cb + (size_t)code * 256 + lane * 4);
    uint2 p;
    p.x = f2bf(ev.x) | (f2bf(ev.y) << 16);
    p.y = f2bf(ev.z) | (f2bf(ev.w) << 16);
    *(uint2*)(smem + r * 516 + lane * 8) = p;
  }
  __syncthreads();
  // ---- b128 pair reads, f32x2 stores (rows r0,r0+1 contiguous in out) ----
  float* outb = out + ((size_t)b << 20) + hw0;
  const int l5 = lane & 31, chf = lane >> 5;
  const int c0 = w * 64 + chf * 32;
#pragma unroll
  for (int h = 0; h < 2; ++h) {
    const int r0 = h * 64 + l5 * 2;
#pragma unroll
    for (int i = 0; i < 4; ++i) {
      const uint4 u0 = *(const uint4*)(smem + r0 * 516 + (c0 + i * 8) * 2);
      const uint4 u1 = *(const uint4*)(smem + (r0 + 1) * 516 + (c0 + i * 8) * 2);
      const ushort* p0 = (const ushort*)&u0;
      const ushort* p1 = (const ushort*)&u1;
#pragma unroll
      for (int j = 0; j < 8; ++j) {
        const int c = c0 + i * 8 + j;
        f32x2v ov;
        ov[0] = __uint_as_float(((unsigned)p0[j]) << 16);
        ov[1] = __uint_as_float(((unsigned)p1[j]) << 16);
        __builtin_nontemporal_store(ov, (f32x2v*)(outb + (size_t)c * 4096 + r0));
      }
    }
  }
}

// =====================================================================
// k3: deterministic reduce of 512 block partials -> vq_loss
// =====================================================================
__global__ __launch_bounds__(256) void k3_loss(const float* __restrict__ pz2,
                                               const float* __restrict__ ps,
                                               float* __restrict__ loss_out) {
  __shared__ double red[256];
  const int t = threadIdx.x;
  double s = ((double)pz2[t] - 2.0 * (double)ps[t]) +
             ((double)pz2[t + 256] - 2.0 * (double)ps[t + 256]);
  red[t] = s;
  __syncthreads();
  for (int st = 128; st; st >>= 1) {
    if (t < st) red[t] += red[t + st];
    __syncthreads();
  }
  if (t == 0) loss_out[0] = (float)(red[0] * (1.25 / 16777216.0));
}

// =====================================================================
extern "C" void kernel_launch(void* const* d_in, const int* in_sizes, int n_in,
                              void* d_out, int out_size, void* d_ws, size_t ws_size,
                              hipStream_t stream) {
  (void)in_sizes; (void)n_in; (void)out_size; (void)ws_size;
  const float* z = (const float*)d_in[0];
  const float* cb = (const float*)d_in[1];
  float* out = (float*)d_out;

  char* wsb = (char*)d_ws;
  char* cbb = wsb;                               // 524288 B (fragment-ordered bf16)
  float* hn = (float*)(wsb + 524288);            //   4096 B
  float* pz2 = (float*)(wsb + 528384);           //   2048 B
  float* ps = (float*)(wsb + 530432);            //   2048 B

  (void)hipFuncSetAttribute((const void*)k1_fused,
                            hipFuncAttributeMaxDynamicSharedMemorySize, LDS_SZ);

  k0b_cb<<<dim3(1024), dim3(64), 0, stream>>>(cb, cbb, hn);
  k1_fused<<<dim3(512), dim3(256), LDS_SZ, stream>>>(z, cb, cbb, hn, out, pz2, ps);
  k3_loss<<<dim3(1), dim3(256), 0, stream>>>(pz2, ps, out + 16777216);
}

// Round 11
// 63.942 us; speedup vs baseline: 1.1021x; 1.1021x over previous
//
#include <hip/hip_runtime.h>
#include <stdint.h>

using bf16x8 = __attribute__((ext_vector_type(8))) __bf16;
using f32x4v = __attribute__((ext_vector_type(4))) float;
using f32x2v = __attribute__((ext_vector_type(2))) float;

__device__ __forceinline__ unsigned int f2bf(float f) {
  unsigned int u = __float_as_uint(f);
  return (u + 0x7FFFu + ((u >> 16) & 1u)) >> 16;  // RNE f32->bf16
}

// =====================================================================
// k0b: codebook f32 [1024][256] -> bf16 in MFMA FRAGMENT order, 32-code
// chunks (16 KB each)  [R8-verified]:
//   addr = (code>>5)*16384 + (((code>>4)&1)*8 + kk)*1024
//          + (g*16 + (code&15))*16 + j*2
// hn = +0.5||e||^2 (negated at k1's LDS copy).
// =====================================================================
__global__ __launch_bounds__(64) void k0b_cb(const float* __restrict__ cb,
                                             char* __restrict__ cbb,
                                             float* __restrict__ hn) {
  const int code = blockIdx.x, l = threadIdx.x;
  const float4 v = *(const float4*)(cb + code * 256 + l * 4);
  float ss = v.x * v.x + v.y * v.y + v.z * v.z + v.w * v.w;
  uint2 p;
  p.x = f2bf(v.x) | (f2bf(v.y) << 16);
  p.y = f2bf(v.z) | (f2bf(v.w) << 16);
  const int addr = ((code >> 5) << 14) +
                   (((((code >> 4) & 1) << 3) + (l >> 3)) << 10) +
                   (((((l >> 1) & 3) << 4) + (code & 15)) << 4) + (l & 1) * 8;
  *(uint2*)(cbb + addr) = p;
#pragma unroll
  for (int s = 32; s; s >>= 1) ss += __shfl_down(ss, s, 64);
  if (l == 0) hn[code] = 0.5f * ss;
}

// =====================================================================
// k1_fused: 1024 blocks x 256 thr (4 waves), block = 64 rows. M=32/wave.
//  - hn folded into MFMA C-init (acc starts at -0.5||e||^2)
//  - packed (score&~1023)|(1023-col) argmax: 3 VALU/score, one max chain
//  - accA/accB alternate; score-update deferred past the chunk's barrier
//    (register-only) -> overlaps next chunk's stage+ds_read+MFMA
// LDS map (38464 B, 4 blocks/CU):
//   region0 [0,33024): A-scratch 32K / B dbuf 2x16K / ef bf16[64][258]
//   hn(neg) [33024,37120) lv [37120,37632) (li region unused)
//   idx [38144,38400) red [38400,38464)
// =====================================================================
#define HN_OFF   33024
#define LV_OFF   37120
#define IDX_OFF  38144
#define RED_OFF  38400
#define LDS_SZ   38464

__global__ __launch_bounds__(256, 4) void k1_fused(const float* __restrict__ z,
                                                   const float* __restrict__ cb,
                                                   const char* __restrict__ cbb,
                                                   const float* __restrict__ hn,
                                                   float* __restrict__ out,
                                                   float* __restrict__ pz2,
                                                   float* __restrict__ ps) {
  extern __shared__ char smem[];
  const int t = threadIdx.x, w = t >> 6, lane = t & 63;
  const int l15 = lane & 15, g4 = lane >> 4;
  const int wr = w >> 1, wc = w & 1;
  const int bid = blockIdx.x;
  const int b = bid >> 6, hw0 = (bid & 63) << 6;
  const float* zb = z + ((size_t)b << 20) + hw0;

  // ---- A stage (R8-verified): 64 rows x 256 ch, float4 loads ----
  const int q = t & 15, oslot = t >> 4;
  float ss = 0.f;
#pragma unroll 1
  for (int oi = 0; oi < 2; ++oi) {
    const int o = oslot + oi * 16;  // channel octet 0..31
    float4 f[8];
#pragma unroll
    for (int j = 0; j < 8; ++j)
      f[j] = *(const float4*)(zb + (size_t)(o * 8 + j) * 4096 + q * 4);
#pragma unroll
    for (int j = 0; j < 8; ++j)
      ss += f[j].x * f[j].x + f[j].y * f[j].y + f[j].z * f[j].z + f[j].w * f[j].w;
    const int kk = o >> 2, g = o & 3;
#pragma unroll
    for (int k = 0; k < 4; ++k) {
      const int row = q * 4 + k;
      const int band = row >> 5, rb = row & 31;
      const int mb = rb >> 4, r15 = rb & 15;
      uint4 q4;
      q4.x = f2bf(((const float*)&f[0])[k]) | (f2bf(((const float*)&f[1])[k]) << 16);
      q4.y = f2bf(((const float*)&f[2])[k]) | (f2bf(((const float*)&f[3])[k]) << 16);
      q4.z = f2bf(((const float*)&f[4])[k]) | (f2bf(((const float*)&f[5])[k]) << 16);
      q4.w = f2bf(((const float*)&f[6])[k]) | (f2bf(((const float*)&f[7])[k]) << 16);
      *(uint4*)(smem + (band << 14) + (((mb << 3) + kk) << 10) + (((g << 4) + r15) << 4)) = q4;
    }
  }
  // hn -> LDS NEGATED (MFMA C-init fold)
  {
    const float4 h = *(const float4*)(hn + 4 * t);
    float4 nh;
    nh.x = -h.x; nh.y = -h.y; nh.z = -h.z; nh.w = -h.w;
    *(float4*)(smem + HN_OFF + t * 16) = nh;
  }
  __syncthreads();

  // ---- A panel -> registers (16 frags = 64 VGPR) ----
  bf16x8 A[2][8];
#pragma unroll
  for (int mb = 0; mb < 2; ++mb)
#pragma unroll
    for (int kk = 0; kk < 8; ++kk)
      A[mb][kk] = *(const bf16x8*)(smem + (wr << 14) + (((mb << 3) + kk) << 10) + (lane << 4));
  __syncthreads();  // scratch reads done before B staging overwrites

  // ---- B chunk stage: 16 KB = 4 issues/wave x 1 KB x 4 waves (R8) ----
  auto stageB = [&](int buf, int ch) {
#pragma unroll
    for (int i = 0; i < 4; ++i) {
      __builtin_amdgcn_global_load_lds(
          (const __attribute__((address_space(1))) unsigned int*)
              (cbb + ((size_t)ch << 14) + (w << 12) + (i << 10) + (lane << 4)),
          (__attribute__((address_space(3))) unsigned int*)
              (smem + (buf << 14) + (w << 12) + (i << 10)),
          16, 0, 0);
    }
  };
  stageB(0, 0);

  const float* hn_s = (const float*)(smem + HN_OFF);
  float bestp[2][4];
#pragma unroll
  for (int m = 0; m < 2; ++m)
#pragma unroll
    for (int i = 0; i < 4; ++i) bestp[m][i] = -3.4e38f;

  __syncthreads();  // buf0 staged (syncthreads drains vmcnt)

  f32x4v accA[2], accB[2];

#define MFMA_CHUNK(ACC, BUF)                                                   \
  __builtin_amdgcn_s_setprio(1);                                               \
  _Pragma("unroll")                                                            \
  for (int kk = 0; kk < 8; ++kk) {                                             \
    const bf16x8 b0 = *(const bf16x8*)(smem + ((BUF) << 14) +                  \
                      ((((wc << 3) + kk)) << 10) + (lane << 4));               \
    ACC[0] = __builtin_amdgcn_mfma_f32_16x16x32_bf16(A[0][kk], b0, ACC[0], 0, 0, 0); \
    ACC[1] = __builtin_amdgcn_mfma_f32_16x16x32_bf16(A[1][kk], b0, ACC[1], 0, 0, 0); \
  }                                                                            \
  __builtin_amdgcn_s_setprio(0);

#define UPDATE_CHUNK(ACC, COL)                                                 \
  {                                                                            \
    const unsigned int iv = 1023u - (unsigned int)(COL);                       \
    _Pragma("unroll")                                                          \
    for (int m = 0; m < 2; ++m)                                                \
      _Pragma("unroll")                                                        \
      for (int i = 0; i < 4; ++i) {                                            \
        const unsigned int u = (__float_as_uint(ACC[m][i]) & 0xFFFFFC00u) | iv;\
        bestp[m][i] = fmaxf(bestp[m][i], __uint_as_float(u));                  \
      }                                                                        \
  }

  // ---- main loop: 16 pairs of chunks; update deferred past barrier ----
  for (int p = 0; p < 16; ++p) {
    const int c0 = 2 * p, c1 = 2 * p + 1;
    // -- chunk c0 (accA, buf0) --
    stageB(1, c1);
    {
      const int colA = c0 * 32 + wc * 16 + l15;
      const float nh = hn_s[colA];
      accA[0] = (f32x4v){nh, nh, nh, nh};
      accA[1] = (f32x4v){nh, nh, nh, nh};
      MFMA_CHUNK(accA, 0)
      __syncthreads();             // c1 DMA drained; buf0 readers done
      UPDATE_CHUNK(accA, colA)     // overlaps next stage + MFMA(accB)
    }
    // -- chunk c1 (accB, buf1) --
    if (p < 15) stageB(0, c0 + 2);
    {
      const int colB = c1 * 32 + wc * 16 + l15;
      const float nh = hn_s[colB];
      accB[0] = (f32x4v){nh, nh, nh, nh};
      accB[1] = (f32x4v){nh, nh, nh, nh};
      MFMA_CHUNK(accB, 1)
      __syncthreads();             // c0+2 DMA drained; buf1 readers done
      UPDATE_CHUNK(accB, colB)     // overlaps next pair's stage + MFMA(accA)
    }
  }

  // ---- cross-lane packed argmax within 16-col groups ----
#pragma unroll
  for (int m = 0; m < 2; ++m)
#pragma unroll
    for (int i = 0; i < 4; ++i) {
      float v = bestp[m][i];
#pragma unroll
      for (int s = 1; s < 16; s <<= 1)
        v = fmaxf(v, __shfl_xor(v, s, 64));
      bestp[m][i] = v;
    }

  float* lv = (float*)(smem + LV_OFF);
  int* idx_s = (int*)(smem + IDX_OFF);
  if (l15 == 0) {
#pragma unroll
    for (int m = 0; m < 2; ++m)
#pragma unroll
      for (int i = 0; i < 4; ++i) {
        const int row = wr * 32 + m * 16 + g4 * 4 + i;
        lv[wc * 64 + row] = bestp[m][i];
      }
  }
  __syncthreads();
  float sv = 0.f;
  if (t < 64) {
    const float pm = fmaxf(lv[t], lv[64 + t]);
    const unsigned int ub = __float_as_uint(pm);
    idx_s[t] = 1023 - (int)(ub & 1023u);
    sv = __uint_as_float(ub & 0xFFFFFC00u);
  }
  // block reductions: pz2 = Sigma z^2 (exact cover), ps = Sigma s*
  float zz = ss;
#pragma unroll
  for (int s = 32; s; s >>= 1) {
    zz += __shfl_down(zz, s, 64);
    sv += __shfl_down(sv, s, 64);
  }
  float* red = (float*)(smem + RED_OFF);
  if (lane == 0) { red[w] = zz; red[4 + w] = sv; }
  __syncthreads();  // idx_s visible; scratch/B dead -> ef may overlay
  if (t == 0) {
    pz2[bid] = red[0] + red[1] + red[2] + red[3];
    ps[bid] = red[4] + red[5] + red[6] + red[7];
  }

  // ---- epilogue: chosen rows -> bf16 ef [64][258] ----
#pragma unroll 4
  for (int rr = 0; rr < 16; ++rr) {
    const int r = w * 16 + rr;
    const int code = idx_s[r];  // wave-uniform broadcast
    const float4 ev = *(const float4*)(cb + (size_t)code * 256 + lane * 4);
    uint2 p;
    p.x = f2bf(ev.x) | (f2bf(ev.y) << 16);
    p.y = f2bf(ev.z) | (f2bf(ev.w) << 16);
    *(uint2*)(smem + r * 516 + lane * 8) = p;
  }
  __syncthreads();
  // ---- b128 pair reads, f32x2 stores (rows r0,r0+1 contiguous) ----
  float* outb = out + ((size_t)b << 20) + hw0;
  const int l5 = lane & 31, chf = lane >> 5;
  const int c0e = w * 64 + chf * 32;
  const int r0 = l5 * 2;
#pragma unroll
  for (int i = 0; i < 4; ++i) {
    const uint4 u0 = *(const uint4*)(smem + r0 * 516 + (c0e + i * 8) * 2);
    const uint4 u1 = *(const uint4*)(smem + (r0 + 1) * 516 + (c0e + i * 8) * 2);
    const ushort* p0 = (const ushort*)&u0;
    const ushort* p1 = (const ushort*)&u1;
#pragma unroll
    for (int j = 0; j < 8; ++j) {
      const int c = c0e + i * 8 + j;
      f32x2v ov;
      ov[0] = __uint_as_float(((unsigned)p0[j]) << 16);
      ov[1] = __uint_as_float(((unsigned)p1[j]) << 16);
      __builtin_nontemporal_store(ov, (f32x2v*)(outb + (size_t)c * 4096 + r0));
    }
  }
}

// =====================================================================
// k3: deterministic reduce of 1024 block partials -> vq_loss
// =====================================================================
__global__ __launch_bounds__(256) void k3_loss(const float* __restrict__ pz2,
                                               const float* __restrict__ ps,
                                               float* __restrict__ loss_out) {
  __shared__ double red[256];
  const int t = threadIdx.x;
  double s = 0.0;
#pragma unroll
  for (int i = 0; i < 4; ++i)
    s += (double)pz2[t * 4 + i] - 2.0 * (double)ps[t * 4 + i];
  red[t] = s;
  __syncthreads();
  for (int st = 128; st; st >>= 1) {
    if (t < st) red[t] += red[t + st];
    __syncthreads();
  }
  if (t == 0) loss_out[0] = (float)(red[0] * (1.25 / 16777216.0));
}

// =====================================================================
extern "C" void kernel_launch(void* const* d_in, const int* in_sizes, int n_in,
                              void* d_out, int out_size, void* d_ws, size_t ws_size,
                              hipStream_t stream) {
  (void)in_sizes; (void)n_in; (void)out_size; (void)ws_size;
  const float* z = (const float*)d_in[0];
  const float* cb = (const float*)d_in[1];
  float* out = (float*)d_out;

  char* wsb = (char*)d_ws;
  char* cbb = wsb;                               // 524288 B (fragment-ordered bf16)
  float* hn = (float*)(wsb + 524288);            //   4096 B
  float* pz2 = (float*)(wsb + 528384);           //   4096 B
  float* ps = (float*)(wsb + 532480);            //   4096 B

  (void)hipFuncSetAttribute((const void*)k1_fused,
                            hipFuncAttributeMaxDynamicSharedMemorySize, LDS_SZ);

  k0b_cb<<<dim3(1024), dim3(64), 0, stream>>>(cb, cbb, hn);
  k1_fused<<<dim3(1024), dim3(256), LDS_SZ, stream>>>(z, cb, cbb, hn, out, pz2, ps);
  k3_loss<<<dim3(1), dim3(256), 0, stream>>>(pz2, ps, out + 16777216);
}